// Round 2
// baseline (139.460 us; speedup 1.0000x reference)
//
#include <hip/hip_runtime.h>

// YOLO layer decode: input (B=16, A*(C+5)=255, H=76, W=76) fp32, anchors (3,2) fp32.
// Output boxes (B, A, H, W, 7): [xs, ys, ws, hs, conf, cls_prob, cls_id].

#define B_  16
#define A_  3
#define C_  80
#define H_  76
#define W_  76
#define PLANE (H_ * W_)   // 5776

__device__ __forceinline__ float fast_exp(float x) {
    // exp(x) = exp2(x * log2(e)) via native v_exp_f32 (which computes 2^x)
    return __builtin_amdgcn_exp2f(x * 1.44269504088896340736f);
}

__device__ __forceinline__ float fast_rcp(float x) {
    return __builtin_amdgcn_rcpf(x);
}

__device__ __forceinline__ float sigmoidf(float x) {
    return fast_rcp(1.0f + fast_exp(-x));
}

__global__ __launch_bounds__(256) void yolo_kernel(const float* __restrict__ in,
                                                   const float* __restrict__ anchors,
                                                   float* __restrict__ out) {
    const int pos = blockIdx.x * 256 + threadIdx.x;   // y*W + x within one (b,a) plane
    if (pos >= PLANE) return;
    const int a = blockIdx.y;   // anchor index
    const int b = blockIdx.z;   // batch index

    const int x = pos % W_;
    const int y = pos / W_;

    const float* base = in + (size_t)(b * (A_ * (C_ + 5)) + a * (C_ + 5)) * PLANE + pos;

    // box channels 0..4
    const float t0 = base[0 * PLANE];
    const float t1 = base[1 * PLANE];
    const float t2 = base[2 * PLANE];
    const float t3 = base[3 * PLANE];
    const float t4 = base[4 * PLANE];

    const float aw = anchors[2 * a + 0];   // wave-uniform: scalar loads
    const float ah = anchors[2 * a + 1];

    const float xs   = (sigmoidf(t0) + (float)x) / (float)W_;
    const float ys   = (sigmoidf(t1) + (float)y) / (float)H_;
    const float ws   = fast_exp(t2) * aw / (float)W_;
    const float hs   = fast_exp(t3) * ah / (float)H_;
    const float conf = sigmoidf(t4);

    // online softmax-max + argmax over the 80 class logits (single pass, no reload)
    const float* cb = base + 5 * PLANE;
    float m = cb[0];
    float s = 1.0f;    // sum of exp(l_i - m), includes the max term
    int   id = 0;
    #pragma unroll 8
    for (int c = 1; c < C_; ++c) {
        const float l  = cb[(size_t)c * PLANE];
        const float e  = fast_exp(l - m);        // exp(l - m_old)
        const bool  gt = l > m;                  // strict > => first-occurrence argmax
        // gt: s_new = s * exp(m_old - l) + 1 = s / e + 1 ; else: s_new = s + e
        s = gt ? __fmaf_rn(s, fast_rcp(e), 1.0f) : (s + e);
        if (gt) { m = l; id = c; }
    }
    const float cls_prob = fast_rcp(s);          // exp(m - m) / s
    const float cls_id   = (float)id;

    const size_t o = (size_t)((b * A_ + a) * PLANE + pos) * 7;
    out[o + 0] = xs;
    out[o + 1] = ys;
    out[o + 2] = ws;
    out[o + 3] = hs;
    out[o + 4] = conf;
    out[o + 5] = cls_prob;
    out[o + 6] = cls_id;
}

extern "C" void kernel_launch(void* const* d_in, const int* in_sizes, int n_in,
                              void* d_out, int out_size, void* d_ws, size_t ws_size,
                              hipStream_t stream) {
    const float* in      = (const float*)d_in[0];
    const float* anchors = (const float*)d_in[1];
    float* out           = (float*)d_out;

    dim3 grid((PLANE + 255) / 256, A_, B_);   // (23, 3, 16)
    dim3 block(256, 1, 1);
    yolo_kernel<<<grid, block, 0, stream>>>(in, anchors, out);
}